// Round 1
// baseline (698.083 us; speedup 1.0000x reference)
//
#include <hip/hip_runtime.h>

typedef __attribute__((ext_vector_type(8))) short bf16x8;
typedef __attribute__((ext_vector_type(4))) float f32x4;

#define LDS_STRIDE 136
#define INV_TEMP 0.08838834764831845f   // 1/sqrt(128)

static __device__ __forceinline__ unsigned short f2b(float f) {
    union { float f; unsigned int u; } v; v.f = f;
    unsigned int b = (v.u + 0x7fffu + ((v.u >> 16) & 1u)) >> 16;
    return (unsigned short)b;
}
static __device__ __forceinline__ float b2f(unsigned short s) {
    union { float f; unsigned int u; } v; v.u = ((unsigned int)s) << 16;
    return v.f;
}

// Convert the four 128x128 fp32 weights to bf16 row-major in workspace.
__global__ void prep_weights(const float* __restrict__ Wq, const float* __restrict__ Wk,
                             const float* __restrict__ Wv, const float* __restrict__ Wo,
                             unsigned short* __restrict__ wbf) {
    int i = blockIdx.x * 256 + threadIdx.x;       // 64 blocks x 256 = 16384
    wbf[i]          = f2b(Wq[i]);
    wbf[16384 + i]  = f2b(Wk[i]);
    wbf[32768 + i]  = f2b(Wv[i]);
    wbf[49152 + i]  = f2b(Wo[i]);
}

__launch_bounds__(512, 2)
__global__ void patch_attn(const float* __restrict__ x,
                           const float* __restrict__ bq, const float* __restrict__ bk,
                           const float* __restrict__ bv, const float* __restrict__ bo,
                           const unsigned short* __restrict__ wbf,
                           float* __restrict__ out)
{
    __shared__ __align__(16) unsigned short sPT[256 * LDS_STRIDE];  // 69,632 B, persistent
    __shared__ __align__(16) unsigned char  sUN[72704];             // time-multiplexed union

    const int tid  = threadIdx.x;
    const int w    = tid >> 6;
    const int lane = tid & 63;
    const int quad = lane >> 4;
    const int l16  = lane & 15;
    const int dcol = w * 16 + l16;     // this wave's output column in all build phases

    const int pid = blockIdx.x;            // 2048 patches
    const int b   = pid >> 10;
    const int n   = pid & 1023;
    const int gy  = n >> 5, gx = n & 31;
    const long patch_off = ((long)(b * 128) * 512 + gy * 16) * 512 + gx * 16;

    const unsigned short* Wq_bf = wbf;
    const unsigned short* Wk_bf = wbf + 16384;
    const unsigned short* Wv_bf = wbf + 32768;
    const unsigned short* Wo_bf = wbf + 49152;

    // ---------------- Phase 0: stage patch token-major (bf16) ----------------
    // Lane-quad holds 4 channels x 4 tokens; 4x4 shfl transpose -> one aligned
    // b64 write of 4 consecutive channels per lane (was 4x ds_write_b16 at
    // 32-way bank conflict).
    {
        const int dc = lane & 3, g = lane >> 2;
        const int l0 = ((w & 3) * 16 + g) * 4;        // 4-token group, same for quad
        const int sh = l0 >> 4, sw = l0 & 15;
        const int cbh = tid >> 8;                     // 0 or 1
        for (int it = 0; it < 16; ++it) {
            const int c0 = (it * 2 + cbh) * 4;        // channel block of 4
            const float4 f = *(const float4*)(x + patch_off + ((long)(c0 + dc) * 512 + sh) * 512 + sw);
            unsigned int A = (unsigned int)f2b(f.x) | ((unsigned int)f2b(f.y) << 16);
            unsigned int B = (unsigned int)f2b(f.z) | ((unsigned int)f2b(f.w) << 16);
            // 4x4 short transpose across the quad (masks 1 then 2)
            unsigned int Pa = __shfl_xor(A, 1);
            unsigned int Pb = __shfl_xor(B, 1);
            unsigned int A1 = (dc & 1) ? ((Pa >> 16) | (A & 0xffff0000u))
                                       : ((A & 0x0000ffffu) | (Pa << 16));
            unsigned int B1 = (dc & 1) ? ((Pb >> 16) | (B & 0xffff0000u))
                                       : ((B & 0x0000ffffu) | (Pb << 16));
            unsigned int Ra = __shfl_xor(A1, 2);
            unsigned int Rb = __shfl_xor(B1, 2);
            uint2 o;
            o.x = (dc & 2) ? Rb : A1;   // channels c0+0,c0+1 at token l0+dc
            o.y = (dc & 2) ? B1 : Ra;   // channels c0+2,c0+3 at token l0+dc
            *(uint2*)&sPT[(l0 + dc) * LDS_STRIDE + c0] = o;
        }
    }
    __syncthreads();

    // ---------------- Phase 1: q-projection (wave w owns d-tile w) -----------
    // Weight frags hoisted to 16 VGPRs; full qscr [256][136] scratch in union.
    unsigned short* qscr = (unsigned short*)sUN;
    {
        bf16x8 wq[4];
#pragma unroll
        for (int ks = 0; ks < 4; ++ks)
            wq[ks] = *(const bf16x8*)(Wq_bf + dcol * 128 + ks * 32 + quad * 8);
        const float qb = bq[dcol];
#pragma unroll
        for (int lt = 0; lt < 16; ++lt) {
            f32x4 acc = {0.f, 0.f, 0.f, 0.f};
#pragma unroll
            for (int ks = 0; ks < 4; ++ks) {
                bf16x8 a = *(const bf16x8*)&sPT[(lt * 16 + l16) * LDS_STRIDE + ks * 32 + quad * 8];
                acc = __builtin_amdgcn_mfma_f32_16x16x32_bf16(a, wq[ks], acc, 0, 0, 0);
            }
#pragma unroll
            for (int r = 0; r < 4; ++r)
                qscr[(lt * 16 + quad * 4 + r) * LDS_STRIDE + dcol] = f2b((acc[r] + qb) * INV_TEMP);
        }
    }
    __syncthreads();
    // read back own 32 rows as A-fragments
    const int lbase = w * 32;
    bf16x8 qfrag[2][4];
#pragma unroll
    for (int lt = 0; lt < 2; ++lt)
#pragma unroll
        for (int ks = 0; ks < 4; ++ks)
            qfrag[lt][ks] = *(const bf16x8*)&qscr[(lbase + lt * 16 + l16) * LDS_STRIDE + ks * 32 + quad * 8];
    __syncthreads();   // release union region for the flash loop

    // ---------------- Phase 2: flash over 4 key-chunks of 64 -----------------
    unsigned short* kTc = (unsigned short*)sUN;                       // [64][136]
    unsigned short* vTc = (unsigned short*)(sUN + 17408);             // [128][72]
    unsigned short* Pw  = (unsigned short*)(sUN + 35840) + w * (32 * 72); // per-wave [32][72]

    // K/V weight frags hoisted across ALL chunks (32 VGPRs)
    bf16x8 wk[4], wv[4];
#pragma unroll
    for (int ks = 0; ks < 4; ++ks) {
        wk[ks] = *(const bf16x8*)(Wk_bf + dcol * 128 + ks * 32 + quad * 8);
        wv[ks] = *(const bf16x8*)(Wv_bf + dcol * 128 + ks * 32 + quad * 8);
    }
    const float kb = bk[dcol], vb = bv[dcol];

    f32x4 O[2][8];
#pragma unroll
    for (int lt = 0; lt < 2; ++lt)
#pragma unroll
        for (int dt = 0; dt < 8; ++dt) O[lt][dt] = (f32x4){0.f, 0.f, 0.f, 0.f};
    float mrow[2][4], lrow[2][4];
#pragma unroll
    for (int lt = 0; lt < 2; ++lt)
#pragma unroll
        for (int r = 0; r < 4; ++r) { mrow[lt][r] = -1e30f; lrow[lt][r] = 0.f; }

    for (int ch = 0; ch < 4; ++ch) {
        const int m0 = ch * 64;
        // build kT-chunk [64][136] and vT-chunk [128][72]; wave w owns d-cols dcol
#pragma unroll
        for (int mt = 0; mt < 4; ++mt) {
            bf16x8 a[4];
#pragma unroll
            for (int ks = 0; ks < 4; ++ks)
                a[ks] = *(const bf16x8*)&sPT[(m0 + mt * 16 + l16) * LDS_STRIDE + ks * 32 + quad * 8];
            f32x4 kacc = {0.f, 0.f, 0.f, 0.f}, vacc = {0.f, 0.f, 0.f, 0.f};
#pragma unroll
            for (int ks = 0; ks < 4; ++ks) {
                kacc = __builtin_amdgcn_mfma_f32_16x16x32_bf16(a[ks], wk[ks], kacc, 0, 0, 0);
                vacc = __builtin_amdgcn_mfma_f32_16x16x32_bf16(a[ks], wv[ks], vacc, 0, 0, 0);
            }
#pragma unroll
            for (int r = 0; r < 4; ++r)
                kTc[(mt * 16 + quad * 4 + r) * LDS_STRIDE + dcol] = f2b(kacc[r] + kb);
            unsigned short vp[4];
#pragma unroll
            for (int r = 0; r < 4; ++r) vp[r] = f2b(vacc[r] + vb);
            unsigned long long pk = (unsigned long long)vp[0]
                                  | ((unsigned long long)vp[1] << 16)
                                  | ((unsigned long long)vp[2] << 32)
                                  | ((unsigned long long)vp[3] << 48);
            *(unsigned long long*)&vTc[dcol * 72 + mt * 16 + quad * 4] = pk;
        }
        __syncthreads();

        // S = q . kT^T, online softmax (defer-max), P -> LDS, O += P . v
#pragma unroll
        for (int lt = 0; lt < 2; ++lt) {
            f32x4 s[4];
#pragma unroll
            for (int nt = 0; nt < 4; ++nt) {
                f32x4 acc = {0.f, 0.f, 0.f, 0.f};
#pragma unroll
                for (int ks = 0; ks < 4; ++ks) {
                    bf16x8 bb = *(const bf16x8*)&kTc[(nt * 16 + l16) * LDS_STRIDE + ks * 32 + quad * 8];
                    acc = __builtin_amdgcn_mfma_f32_16x16x32_bf16(qfrag[lt][ks], bb, acc, 0, 0, 0);
                }
                s[nt] = acc;
            }
            float mx[4];
#pragma unroll
            for (int r = 0; r < 4; ++r) {
                float m = fmaxf(fmaxf(s[0][r], s[1][r]), fmaxf(s[2][r], s[3][r]));
#pragma unroll
                for (int off = 8; off; off >>= 1) m = fmaxf(m, __shfl_xor(m, off));
                mx[r] = m;
            }
            // T13 defer-max: skip the O-wide rescale while growth <= 8 (exact math,
            // P bounded by e^8). First chunk always takes the rescale path.
            bool need = false;
#pragma unroll
            for (int r = 0; r < 4; ++r) need |= (mx[r] - mrow[lt][r] > 8.f);
            if (__any(need)) {
#pragma unroll
                for (int r = 0; r < 4; ++r) {
                    float mnew  = fmaxf(mrow[lt][r], mx[r]);
                    float alpha = __expf(mrow[lt][r] - mnew);
                    mrow[lt][r] = mnew;
                    lrow[lt][r] *= alpha;
#pragma unroll
                    for (int dt = 0; dt < 8; ++dt) O[lt][dt][r] *= alpha;
                }
            }
#pragma unroll
            for (int r = 0; r < 4; ++r) {
                float rs = 0.f;
#pragma unroll
                for (int nt = 0; nt < 4; ++nt) {
                    float p = __expf(s[nt][r] - mrow[lt][r]);
                    s[nt][r] = p;
                    rs += p;
                }
#pragma unroll
                for (int off = 8; off; off >>= 1) rs += __shfl_xor(rs, off);
                lrow[lt][r] += rs;
            }
#pragma unroll
            for (int nt = 0; nt < 4; ++nt)
#pragma unroll
                for (int r = 0; r < 4; ++r)
                    Pw[(lt * 16 + quad * 4 + r) * 72 + nt * 16 + l16] = f2b(s[nt][r]);
#pragma unroll
            for (int dt = 0; dt < 8; ++dt) {
                f32x4 acc = O[lt][dt];
#pragma unroll
                for (int kt = 0; kt < 2; ++kt) {
                    bf16x8 pa = *(const bf16x8*)&Pw[(lt * 16 + l16) * 72 + kt * 32 + quad * 8];
                    bf16x8 vv = *(const bf16x8*)&vTc[(dt * 16 + l16) * 72 + kt * 32 + quad * 8];
                    acc = __builtin_amdgcn_mfma_f32_16x16x32_bf16(pa, vv, acc, 0, 0, 0);
                }
                O[lt][dt] = acc;
            }
        }
        __syncthreads();   // protect kTc/vTc overwrite next chunk (and yA reuse after)
    }

    // ---------------- Phase 3: normalize, O-projection, residual, store ------
    unsigned short* yA = (unsigned short*)sUN;   // [256][136] (flash region is dead)
#pragma unroll
    for (int lt = 0; lt < 2; ++lt) {
        float inv[4];
#pragma unroll
        for (int r = 0; r < 4; ++r) inv[r] = 1.f / lrow[lt][r];
#pragma unroll
        for (int dt = 0; dt < 8; ++dt)
#pragma unroll
            for (int r = 0; r < 4; ++r)
                yA[(lbase + lt * 16 + quad * 4 + r) * LDS_STRIDE + dt * 16 + l16] =
                    f2b(O[lt][dt][r] * inv[r]);
    }
    __syncthreads();   // wave w now reads ALL rows of yA

    {
        bf16x8 wo[4];
#pragma unroll
        for (int ks = 0; ks < 4; ++ks)
            wo[ks] = *(const bf16x8*)(Wo_bf + dcol * 128 + ks * 32 + quad * 8);
        const float ob = bo[dcol];
        float* outc = out + patch_off + (long)dcol * 262144;
#pragma unroll
        for (int lt = 0; lt < 16; ++lt) {
            f32x4 acc = {0.f, 0.f, 0.f, 0.f};
#pragma unroll
            for (int ks = 0; ks < 4; ++ks) {
                bf16x8 a = *(const bf16x8*)&yA[(lt * 16 + l16) * LDS_STRIDE + ks * 32 + quad * 8];
                acc = __builtin_amdgcn_mfma_f32_16x16x32_bf16(a, wo[ks], acc, 0, 0, 0);
            }
            f32x4 o4;
#pragma unroll
            for (int r = 0; r < 4; ++r)
                o4[r] = acc[r] + ob + b2f(sPT[(lt * 16 + quad * 4 + r) * LDS_STRIDE + dcol]);
            *(f32x4*)(outc + lt * 512 + quad * 4) = o4;   // rows quad*4+r are consecutive sw
        }
    }
}

extern "C" void kernel_launch(void* const* d_in, const int* in_sizes, int n_in,
                              void* d_out, int out_size, void* d_ws, size_t ws_size,
                              hipStream_t stream) {
    (void)in_sizes; (void)n_in; (void)out_size; (void)ws_size;
    const float* x  = (const float*)d_in[0];
    const float* Wq = (const float*)d_in[1];
    const float* bq = (const float*)d_in[2];
    const float* Wk = (const float*)d_in[3];
    const float* bk = (const float*)d_in[4];
    const float* Wv = (const float*)d_in[5];
    const float* bv = (const float*)d_in[6];
    const float* Wo = (const float*)d_in[7];
    const float* bo = (const float*)d_in[8];
    unsigned short* wbf = (unsigned short*)d_ws;   // 131,072 B of bf16 weights

    prep_weights<<<64, 256, 0, stream>>>(Wq, Wk, Wv, Wo, wbf);
    patch_attn<<<2048, 512, 0, stream>>>(x, bq, bk, bv, bo, wbf, (float*)d_out);
}